// Round 6
// baseline (471.323 us; speedup 1.0000x reference)
//
#include <hip/hip_runtime.h>
#include <math.h>

#define HID 64
#define KIN 512
#define NBK_MAX 256

typedef __attribute__((ext_vector_type(8))) short short8;   // 8 bf16 (4 VGPR)
typedef __attribute__((ext_vector_type(4))) float floatx4;  // MFMA acc
typedef __attribute__((ext_vector_type(2))) float floatx2;

// RNE fp32 -> bf16
__device__ inline unsigned bf16pair(float a, float b) {
  unsigned ua = __float_as_uint(a);
  unsigned ub = __float_as_uint(b);
  ua = (ua + 0x7FFFu + ((ua >> 16) & 1u)) >> 16;
  ub = (ub + 0x7FFFu + ((ub >> 16) & 1u)) >> 16;
  return ua | (ub << 16);
}
__device__ inline unsigned short bf16one(float a) {
  unsigned ua = __float_as_uint(a);
  return (unsigned short)((ua + 0x7FFFu + ((ua >> 16) & 1u)) >> 16);
}
// fp8 e4m3 (OCP) quantize one float -> byte, via HW pack cvt
__device__ inline unsigned char fp8q(float a) {
  const int pk = __builtin_amdgcn_cvt_pk_fp8_f32(a, a, 0, false);
  return (unsigned char)(pk & 0xff);
}

// ==== K1: weight prep (blocks 0..55) + bucket partition of edges by dst>>9
// (single pass; degrees derived later by the scatter blocks) ====
__global__ __launch_bounds__(1024) void prep_bucket_kernel(
    const float* __restrict__ We, const float* __restrict__ Wl,
    const float* __restrict__ Wr, unsigned short* __restrict__ wte,
    unsigned short* __restrict__ wlrt, const int* __restrict__ src,
    const int* __restrict__ dst, int* __restrict__ gcur,
    unsigned* __restrict__ ebuf, int E, int N, int NBK, int CAP) {
  const int blk = blockIdx.x;
  const int tid = threadIdx.x;
  if (blk < 32) {  // encoder weight transpose: 64*512 = 32768 elems
    const int t = blk * 1024 + tid;
    const int c = t >> 9, k = t & 511;
    wte[c * KIN + k] = bf16one(We[k * HID + c]);
    return;
  }
  if (blk < 56) {  // layer weight transposes: 6*64*64 = 24576 elems
    const int t = (blk - 32) * 1024 + tid;
    if (t < 24576) {
      const int mat = t >> 12;
      const int e = t & 4095;
      const int c = e >> 6, k = e & 63;
      const float* sp = (mat < 3) ? (Wl + (size_t)mat * 4096)
                                  : (Wr + (size_t)(mat - 3) * 4096);
      wlrt[(size_t)mat * 4096 + c * 64 + k] = bf16one(sp[k * 64 + c]);
    }
    return;
  }
  // ---- bucket partition: 4096 edges per block ----
  __shared__ int hist[NBK_MAX];
  __shared__ int bbase[NBK_MAX];
  __shared__ int curloc[NBK_MAX];
  const int e0 = (blk - 56) * 4096;
  for (int i = tid; i < NBK; i += 1024) {
    hist[i] = 0;
    curloc[i] = 0;
  }
  __syncthreads();
  int bk[4];
  unsigned pk[4];
#pragma unroll
  for (int u = 0; u < 4; u++) {
    const int e = e0 + u * 1024 + tid;
    bk[u] = -1;
    pk[u] = 0;
    if (e < E) {
      const int d = dst[e];
      if ((unsigned)d < (unsigned)N) {
        int s = src[e];
        if ((unsigned)s >= (unsigned)N) s = 0;
        bk[u] = d >> 9;
        pk[u] = ((unsigned)s << 9) | (unsigned)(d & 511);
        atomicAdd(&hist[bk[u]], 1);
      }
    }
  }
  __syncthreads();
  // reserve one contiguous run per (block, bucket)
  for (int i = tid; i < NBK; i += 1024)
    if (hist[i]) bbase[i] = atomicAdd(&gcur[i], hist[i]);
  __syncthreads();
#pragma unroll
  for (int u = 0; u < 4; u++) {
    if (bk[u] >= 0) {
      const int gp = bbase[bk[u]] + atomicAdd(&curloc[bk[u]], 1);
      if (gp < CAP) ebuf[(size_t)bk[u] * CAP + gp] = pk[u];
    }
  }
}

// ==== K2: bucket-local {degree count + prefix + CSR scatter} (blocks
// 0..NBK-1) + encoder (blocks NBK..): barrier-free direct-from-global MFMA.
// A-frag = 32B of x (cvt to bf16); B-frag = 16B of wte; no LDS in encoder.
__global__ __launch_bounds__(256) void scatter_enc_kernel(
    const unsigned* __restrict__ ebuf, const int* __restrict__ gcur,
    int* __restrict__ row_start, float* __restrict__ inv_deg,
    int* __restrict__ csr_src, const float* __restrict__ x,
    const unsigned short* __restrict__ wt, const float* __restrict__ b,
    unsigned short* __restrict__ hb, unsigned char* __restrict__ h8, int N,
    int NBK, int CAP) {
  __shared__ int cur[512];
  __shared__ int rsl[512];
  __shared__ int psc[256];
  __shared__ int soffp;
  if (blockIdx.x < (unsigned)NBK) {
    const int bkt = blockIdx.x;
    const int nodeBase = bkt << 9;
    const int tid = threadIdx.x;
    cur[tid] = 0;
    cur[tid + 256] = 0;
    __syncthreads();
    int cnt_b = gcur[bkt];
    if (cnt_b > CAP) cnt_b = CAP;
    const unsigned* eb = ebuf + (size_t)bkt * CAP;
    // pass 1: per-node degree via LDS atomics
    for (int i = tid; i < cnt_b; i += 256) atomicAdd(&cur[eb[i] & 511], 1);
    // bucket global offset = sum of preceding buckets' edge counts
    if (tid < 64) {
      int s = 0;
      for (int b2 = tid; b2 < bkt; b2 += 64) s += gcur[b2];
#pragma unroll
      for (int off = 32; off > 0; off >>= 1) s += __shfl_down(s, off, 64);
      if (tid == 0) soffp = s;
    }
    __syncthreads();
    // local exclusive prefix over 512 degrees (pairwise + Hillis-Steele)
    const int d0 = cur[2 * tid];
    const int d1 = cur[2 * tid + 1];
    psc[tid] = d0 + d1;
    __syncthreads();
    for (int off = 1; off < 256; off <<= 1) {
      int t = (tid >= off) ? psc[tid - off] : 0;
      __syncthreads();
      psc[tid] += t;
      __syncthreads();
    }
    const int soff = soffp;
    const int base0 = soff + psc[tid] - (d0 + d1);
    rsl[2 * tid] = base0;
    rsl[2 * tid + 1] = base0 + d0;
    const int g0 = nodeBase + 2 * tid;
    const int g1 = g0 + 1;
    if (g0 < N) {
      row_start[g0] = base0;
      inv_deg[g0] = d0 ? 1.0f / (float)d0 : 0.f;
    }
    if (g1 < N) {
      row_start[g1] = base0 + d0;
      inv_deg[g1] = d1 ? 1.0f / (float)d1 : 0.f;
    }
    if (bkt == NBK - 1 && tid == 255) row_start[N] = soff + psc[255];
    // reset cursors for pass 2
    cur[tid] = 0;
    cur[tid + 256] = 0;
    __syncthreads();
    // pass 2: rank-based scatter into the bucket's contiguous CSR window
    for (int i = tid; i < cnt_b; i += 256) {
      const unsigned p = eb[i];
      const int dl = p & 511;
      const int pos = rsl[dl] + atomicAdd(&cur[dl], 1);
      csr_src[pos] = (int)(p >> 9);
    }
    return;
  }
  // ---- encoder: barrier-free, LDS-free ----
  const int t = threadIdx.x;
  const int lane = t & 63;
  const int wid = t >> 6;
  const int m15 = lane & 15;
  const int quad = lane >> 4;
  const int blockBase = (blockIdx.x - NBK) * 64;

  const int arow = blockBase + wid * 16 + m15;  // this lane's A row (global)
  const bool valid = arow < N;
  const float* xp = x + (size_t)(valid ? arow : 0) * KIN + quad * 8;
  // B-fragment pointers: col c4*16+m15, k-slice quad*8
  const unsigned short* wp0 = wt + (size_t)m15 * KIN + quad * 8;
  const unsigned short* wp1 = wp0 + (size_t)16 * KIN;
  const unsigned short* wp2 = wp0 + (size_t)32 * KIN;
  const unsigned short* wp3 = wp0 + (size_t)48 * KIN;

  floatx4 acc[4];
#pragma unroll
  for (int c4 = 0; c4 < 4; c4++)
#pragma unroll
    for (int j = 0; j < 4; j++) acc[c4][j] = 0.f;

#pragma unroll 4
  for (int kc = 0; kc < 16; kc++) {
    float4 fx0, fx1;
    if (valid) {
      fx0 = *(const float4*)(xp + kc * 32);
      fx1 = *(const float4*)(xp + kc * 32 + 4);
    } else {
      fx0 = fx1 = make_float4(0.f, 0.f, 0.f, 0.f);
    }
    uint4 xu;
    xu.x = bf16pair(fx0.x, fx0.y);
    xu.y = bf16pair(fx0.z, fx0.w);
    xu.z = bf16pair(fx1.x, fx1.y);
    xu.w = bf16pair(fx1.z, fx1.w);
    const short8 a = __builtin_bit_cast(short8, xu);
    const uint4 wv0 = *(const uint4*)(wp0 + kc * 32);
    const uint4 wv1 = *(const uint4*)(wp1 + kc * 32);
    const uint4 wv2 = *(const uint4*)(wp2 + kc * 32);
    const uint4 wv3 = *(const uint4*)(wp3 + kc * 32);
    acc[0] = __builtin_amdgcn_mfma_f32_16x16x32_bf16(
        a, __builtin_bit_cast(short8, wv0), acc[0], 0, 0, 0);
    acc[1] = __builtin_amdgcn_mfma_f32_16x16x32_bf16(
        a, __builtin_bit_cast(short8, wv1), acc[1], 0, 0, 0);
    acc[2] = __builtin_amdgcn_mfma_f32_16x16x32_bf16(
        a, __builtin_bit_cast(short8, wv2), acc[2], 0, 0, 0);
    acc[3] = __builtin_amdgcn_mfma_f32_16x16x32_bf16(
        a, __builtin_bit_cast(short8, wv3), acc[3], 0, 0, 0);
  }

#pragma unroll
  for (int c4 = 0; c4 < 4; c4++) {
    const float bias = b[c4 * 16 + m15];
#pragma unroll
    for (int r = 0; r < 4; r++) {
      const int row = blockBase + wid * 16 + quad * 4 + r;
      if (row < N) {
        const float v = acc[c4][r] + bias;
        hb[(size_t)row * HID + c4 * 16 + m15] = bf16one(v);
        h8[(size_t)row * HID + c4 * 16 + m15] = fp8q(v);
      }
    }
  }
}

// ===== fused layer: fp8 gather-mean -> [agg|h]@[Wl;Wr] MFMA -> residual/relu
//       -> bf16(+fp8) store (+ optional classifier on last layer) =====
// Round-2 structure (proven): Wl/Wr LDS-staged, 32 KB LDS total
__global__ __launch_bounds__(256) void layer_kernel(
    const unsigned short* __restrict__ hin,
    const unsigned char* __restrict__ h8in, unsigned short* __restrict__ hout,
    unsigned char* __restrict__ h8out, const int* __restrict__ row_start,
    const int* __restrict__ csr_src, const float* __restrict__ inv_deg,
    const unsigned short* __restrict__ Wlt,
    const unsigned short* __restrict__ Wrt, const float* __restrict__ bl,
    const float* __restrict__ Wc, const float* __restrict__ bc,
    float* __restrict__ out, int N) {
  __shared__ uint4 sAgg[512];  // 8 KB agg tile (bf16)
  __shared__ uint4 sH[512];    // 8 KB own h rows (bf16)
  __shared__ uint4 sWl[512];   // 8 KB Wl^T bf16
  __shared__ uint4 sWr[512];   // 8 KB Wr^T bf16
  const int tid = threadIdx.x;
  const int lane = tid & 63;
  const int wid = tid >> 6;
  const int m15 = lane & 15;
  const int quad = lane >> 4;
  const int blockBase = blockIdx.x * 64;

  // ---- stage own h rows + both weight mats ----
  {
    const int r = tid >> 2;
    const int gp = tid & 3;
    const int g0 = gp * 2, g1 = gp * 2 + 1;
    const int u0 = r * 8 + (g0 ^ (r & 7));
    const int u1 = r * 8 + (g1 ^ (r & 7));
    const int gn = blockBase + r;
    if (gn < N) {
      const uint4* hp = (const uint4*)(hin + (size_t)gn * HID);
      sH[u0] = hp[g0];
      sH[u1] = hp[g1];
    } else {
      const uint4 z = make_uint4(0, 0, 0, 0);
      sH[u0] = z;
      sH[u1] = z;
    }
    const uint4* wl = (const uint4*)(Wlt + (size_t)r * HID);
    const uint4* wr = (const uint4*)(Wrt + (size_t)r * HID);
    sWl[u0] = wl[g0];
    sWl[u1] = wl[g1];
    sWr[u0] = wr[g0];
    sWr[u1] = wr[g1];
  }

  // ---- mean-aggregate neighbors (fp8 rows) into sAgg ----
  {
    const int slot = lane >> 2;  // 0..15: node slot
    const int qc = lane & 3;     // 0..3: 16B group (16 fp8 cols)
    const int nl = wid * 16 + slot;
    const int gn = blockBase + nl;
    float a[16];
#pragma unroll
    for (int c = 0; c < 16; c++) a[c] = 0.f;
    float id = 0.f;
    if (gn < N) {
      id = inv_deg[gn];
      const int s = row_start[gn];
      const int e = row_start[gn + 1];
      for (int j = s; j < e; j += 8) {
        int n[8];
        bool ok[8];
#pragma unroll
        for (int u = 0; u < 8; u++) {
          const int jj = j + u;
          ok[u] = jj < e;
          n[u] = csr_src[ok[u] ? jj : j];
        }
        uint4 v[8];
#pragma unroll
        for (int u = 0; u < 8; u++) {
          v[u] = *(const uint4*)(h8in + (size_t)n[u] * HID + qc * 16);
        }
#pragma unroll
        for (int u = 0; u < 8; u++) {
          if (!ok[u]) v[u] = make_uint4(0, 0, 0, 0);
#if __has_builtin(__builtin_amdgcn_cvt_pk_f32_fp8)
          {
            floatx2 p;
            p = __builtin_amdgcn_cvt_pk_f32_fp8((int)v[u].x, false);
            a[0] += p[0]; a[1] += p[1];
            p = __builtin_amdgcn_cvt_pk_f32_fp8((int)v[u].x, true);
            a[2] += p[0]; a[3] += p[1];
            p = __builtin_amdgcn_cvt_pk_f32_fp8((int)v[u].y, false);
            a[4] += p[0]; a[5] += p[1];
            p = __builtin_amdgcn_cvt_pk_f32_fp8((int)v[u].y, true);
            a[6] += p[0]; a[7] += p[1];
            p = __builtin_amdgcn_cvt_pk_f32_fp8((int)v[u].z, false);
            a[8] += p[0]; a[9] += p[1];
            p = __builtin_amdgcn_cvt_pk_f32_fp8((int)v[u].z, true);
            a[10] += p[0]; a[11] += p[1];
            p = __builtin_amdgcn_cvt_pk_f32_fp8((int)v[u].w, false);
            a[12] += p[0]; a[13] += p[1];
            p = __builtin_amdgcn_cvt_pk_f32_fp8((int)v[u].w, true);
            a[14] += p[0]; a[15] += p[1];
          }
#else
          a[0] += __builtin_amdgcn_cvt_f32_fp8(v[u].x, 0);
          a[1] += __builtin_amdgcn_cvt_f32_fp8(v[u].x, 1);
          a[2] += __builtin_amdgcn_cvt_f32_fp8(v[u].x, 2);
          a[3] += __builtin_amdgcn_cvt_f32_fp8(v[u].x, 3);
          a[4] += __builtin_amdgcn_cvt_f32_fp8(v[u].y, 0);
          a[5] += __builtin_amdgcn_cvt_f32_fp8(v[u].y, 1);
          a[6] += __builtin_amdgcn_cvt_f32_fp8(v[u].y, 2);
          a[7] += __builtin_amdgcn_cvt_f32_fp8(v[u].y, 3);
          a[8] += __builtin_amdgcn_cvt_f32_fp8(v[u].z, 0);
          a[9] += __builtin_amdgcn_cvt_f32_fp8(v[u].z, 1);
          a[10] += __builtin_amdgcn_cvt_f32_fp8(v[u].z, 2);
          a[11] += __builtin_amdgcn_cvt_f32_fp8(v[u].z, 3);
          a[12] += __builtin_amdgcn_cvt_f32_fp8(v[u].w, 0);
          a[13] += __builtin_amdgcn_cvt_f32_fp8(v[u].w, 1);
          a[14] += __builtin_amdgcn_cvt_f32_fp8(v[u].w, 2);
          a[15] += __builtin_amdgcn_cvt_f32_fp8(v[u].w, 3);
#endif
        }
      }
    }
    uint4 p0, p1;
    p0.x = bf16pair(a[0] * id, a[1] * id);
    p0.y = bf16pair(a[2] * id, a[3] * id);
    p0.z = bf16pair(a[4] * id, a[5] * id);
    p0.w = bf16pair(a[6] * id, a[7] * id);
    p1.x = bf16pair(a[8] * id, a[9] * id);
    p1.y = bf16pair(a[10] * id, a[11] * id);
    p1.z = bf16pair(a[12] * id, a[13] * id);
    p1.w = bf16pair(a[14] * id, a[15] * id);
    sAgg[nl * 8 + ((qc * 2) ^ (nl & 7))] = p0;
    sAgg[nl * 8 + ((qc * 2 + 1) ^ (nl & 7))] = p1;
  }
  __syncthreads();

  // ---- MFMA: acc = agg@Wl + h@Wr ----
  floatx4 acc[4];
#pragma unroll
  for (int c4 = 0; c4 < 4; c4++)
#pragma unroll
    for (int j = 0; j < 4; j++) acc[c4][j] = 0.f;

  const int arow = wid * 16 + m15;
#pragma unroll
  for (int c = 0; c < 2; c++) {
    const int ua = arow * 8 + ((c * 4 + quad) ^ (arow & 7));
    const short8 aA = __builtin_bit_cast(short8, sAgg[ua]);
    const short8 aH = __builtin_bit_cast(short8, sH[ua]);
#pragma unroll
    for (int c4 = 0; c4 < 4; c4++) {
      const int col = c4 * 16 + m15;
      const int ub = col * 8 + ((c * 4 + quad) ^ (col & 7));
      acc[c4] = __builtin_amdgcn_mfma_f32_16x16x32_bf16(
          aA, __builtin_bit_cast(short8, sWl[ub]), acc[c4], 0, 0, 0);
      acc[c4] = __builtin_amdgcn_mfma_f32_16x16x32_bf16(
          aH, __builtin_bit_cast(short8, sWr[ub]), acc[c4], 0, 0, 0);
    }
  }

  // ---- epilogue: residual + bias + relu; bf16(+fp8) store; optional cls ----
  float vals[4][4];
#pragma unroll
  for (int c4 = 0; c4 < 4; c4++) {
    const float bias = bl[c4 * 16 + m15];
#pragma unroll
    for (int r = 0; r < 4; r++) {
      const int rowl = wid * 16 + quad * 4 + r;
      const unsigned short hv =
          ((const unsigned short*)
               sH)[(rowl * 8 + ((c4 * 2 + (m15 >> 3)) ^ (rowl & 7))) * 8 +
                   (m15 & 7)];
      const float v = __uint_as_float((unsigned)hv << 16) + acc[c4][r] + bias;
      vals[c4][r] = v > 0.f ? v : 0.f;
    }
  }
#pragma unroll
  for (int c4 = 0; c4 < 4; c4++) {
#pragma unroll
    for (int r = 0; r < 4; r++) {
      const int rowg = blockBase + wid * 16 + quad * 4 + r;
      if (rowg < N)
        hout[(size_t)rowg * HID + c4 * 16 + m15] = bf16one(vals[c4][r]);
    }
  }
  if (h8out != nullptr) {
#pragma unroll
    for (int c4 = 0; c4 < 4; c4++) {
#pragma unroll
      for (int r = 0; r < 4; r++) {
        const int rowg = blockBase + wid * 16 + quad * 4 + r;
        if (rowg < N)
          h8out[(size_t)rowg * HID + c4 * 16 + m15] = fp8q(vals[c4][r]);
      }
    }
  }
  if (Wc != nullptr) {
    float p[4] = {0.f, 0.f, 0.f, 0.f};
#pragma unroll
    for (int c4 = 0; c4 < 4; c4++) {
      const float wc = Wc[c4 * 16 + m15];
#pragma unroll
      for (int r = 0; r < 4; r++) p[r] += vals[c4][r] * wc;
    }
#pragma unroll
    for (int off = 1; off < 16; off <<= 1) {
#pragma unroll
      for (int r = 0; r < 4; r++) p[r] += __shfl_xor(p[r], off, 16);
    }
    if (m15 == 0) {
      const float bb = bc[0];
#pragma unroll
      for (int r = 0; r < 4; r++) {
        const int rowg = blockBase + wid * 16 + quad * 4 + r;
        if (rowg < N) out[rowg] = 1.0f / (1.0f + expf(-(p[r] + bb)));
      }
    }
  }
}

extern "C" void kernel_launch(void* const* d_in, const int* in_sizes, int n_in,
                              void* d_out, int out_size, void* d_ws,
                              size_t ws_size, hipStream_t stream) {
  const float* x = (const float*)d_in[0];
  const int* ei = (const int*)d_in[1];
  const float* W_enc = (const float*)d_in[2];
  const float* b_enc = (const float*)d_in[3];
  const float* Wl = (const float*)d_in[4];
  const float* bl = (const float*)d_in[5];
  const float* Wr = (const float*)d_in[6];
  const float* Wc = (const float*)d_in[7];
  const float* bc = (const float*)d_in[8];
  float* out = (float*)d_out;

  const int N = in_sizes[0] / KIN;
  const int E = in_sizes[1] / 2;
  const int* src = ei;
  const int* dst = ei + E;

  const int NBK = (N + 511) >> 9;  // 512-node buckets
  int CAP = E / (NBK > 0 ? NBK : 1);
  CAP = CAP + (CAP >> 1) + 1024;  // 1.5x mean + slack (>>20 sigma headroom)
  CAP = (CAP + 255) & ~255;

  char* ws = (char*)d_ws;
  size_t off = 0;
  auto alloc = [&](size_t bytes) -> void* {
    void* p = ws + off;
    off += (bytes + 255) & ~(size_t)255;
    return p;
  };
  unsigned short* hb0 =
      (unsigned short*)alloc((size_t)N * HID * sizeof(unsigned short));
  unsigned short* hb1 =
      (unsigned short*)alloc((size_t)N * HID * sizeof(unsigned short));
  unsigned char* h8a = (unsigned char*)alloc((size_t)N * HID);
  unsigned char* h8b = (unsigned char*)alloc((size_t)N * HID);
  int* gcur = (int*)alloc((size_t)NBK * sizeof(int));  // zeroed below
  int* row_start = (int*)alloc((size_t)(N + 1) * sizeof(int));
  float* inv_deg = (float*)alloc((size_t)N * sizeof(float));
  int* csr_src = (int*)alloc((size_t)E * sizeof(int));
  unsigned* ebuf = (unsigned*)alloc((size_t)NBK * CAP * sizeof(unsigned));
  unsigned short* wte =
      (unsigned short*)alloc((size_t)HID * KIN * sizeof(unsigned short));
  unsigned short* wlrt =
      (unsigned short*)alloc((size_t)6 * HID * HID * sizeof(unsigned short));

  hipMemsetAsync(gcur, 0, (size_t)NBK * sizeof(int), stream);

  const int nbktA = (E + 4095) / 4096;
  prep_bucket_kernel<<<56 + nbktA, 1024, 0, stream>>>(
      W_enc, Wl, Wr, wte, wlrt, src, dst, gcur, ebuf, E, N, NBK, CAP);
  const int nb64 = (N + 63) / 64;
  scatter_enc_kernel<<<NBK + nb64, 256, 0, stream>>>(
      ebuf, gcur, row_start, inv_deg, csr_src, x, wte, b_enc, hb0, h8a, N, NBK,
      CAP);

  // layer 0: hb0/h8a -> hb1/h8b
  layer_kernel<<<nb64, 256, 0, stream>>>(hb0, h8a, hb1, h8b, row_start, csr_src,
                                         inv_deg, wlrt, wlrt + 3 * 4096, bl,
                                         nullptr, nullptr, nullptr, N);
  // layer 1: hb1/h8b -> hb0/h8a
  layer_kernel<<<nb64, 256, 0, stream>>>(hb1, h8b, hb0, h8a, row_start, csr_src,
                                         inv_deg, wlrt + 4096, wlrt + 4 * 4096,
                                         bl + 64, nullptr, nullptr, nullptr, N);
  // layer 2: hb0/h8a -> hb1 (no fp8 out), fused classifier
  layer_kernel<<<nb64, 256, 0, stream>>>(hb0, h8a, hb1, nullptr, row_start,
                                         csr_src, inv_deg, wlrt + 2 * 4096,
                                         wlrt + 5 * 4096, bl + 128, Wc, bc, out,
                                         N);
}

// Round 7
// 430.880 us; speedup vs baseline: 1.0939x; 1.0939x over previous
//
#include <hip/hip_runtime.h>
#include <math.h>

#define HID 64
#define KIN 512
#define NBK_MAX 256

typedef __attribute__((ext_vector_type(8))) short short8;   // 8 bf16 (4 VGPR)
typedef __attribute__((ext_vector_type(4))) float floatx4;  // MFMA acc
typedef __attribute__((ext_vector_type(2))) float floatx2;

// RNE fp32 -> bf16
__device__ inline unsigned bf16pair(float a, float b) {
  unsigned ua = __float_as_uint(a);
  unsigned ub = __float_as_uint(b);
  ua = (ua + 0x7FFFu + ((ua >> 16) & 1u)) >> 16;
  ub = (ub + 0x7FFFu + ((ub >> 16) & 1u)) >> 16;
  return ua | (ub << 16);
}
__device__ inline unsigned short bf16one(float a) {
  unsigned ua = __float_as_uint(a);
  return (unsigned short)((ua + 0x7FFFu + ((ua >> 16) & 1u)) >> 16);
}
// fp8 e4m3 (OCP) quantize one float -> byte, via HW pack cvt
__device__ inline unsigned char fp8q(float a) {
  const int pk = __builtin_amdgcn_cvt_pk_fp8_f32(a, a, 0, false);
  return (unsigned char)(pk & 0xff);
}

// ==== K1: weight prep (blocks 0..55) + bucket partition of edges by dst>>9
// (single pass; degrees derived later by the scatter blocks).
// 8192 edges/block: halves gcur global-atomic count vs 4096/block. ====
__global__ __launch_bounds__(1024) void prep_bucket_kernel(
    const float* __restrict__ We, const float* __restrict__ Wl,
    const float* __restrict__ Wr, unsigned short* __restrict__ wte,
    unsigned short* __restrict__ wlrt, const int* __restrict__ src,
    const int* __restrict__ dst, int* __restrict__ gcur,
    unsigned* __restrict__ ebuf, int E, int N, int NBK, int CAP) {
  const int blk = blockIdx.x;
  const int tid = threadIdx.x;
  if (blk < 32) {  // encoder weight transpose: 64*512 = 32768 elems
    const int t = blk * 1024 + tid;
    const int c = t >> 9, k = t & 511;
    wte[c * KIN + k] = bf16one(We[k * HID + c]);
    return;
  }
  if (blk < 56) {  // layer weight transposes: 6*64*64 = 24576 elems
    const int t = (blk - 32) * 1024 + tid;
    if (t < 24576) {
      const int mat = t >> 12;
      const int e = t & 4095;
      const int c = e >> 6, k = e & 63;
      const float* sp = (mat < 3) ? (Wl + (size_t)mat * 4096)
                                  : (Wr + (size_t)(mat - 3) * 4096);
      wlrt[(size_t)mat * 4096 + c * 64 + k] = bf16one(sp[k * 64 + c]);
    }
    return;
  }
  // ---- bucket partition: 8192 edges per block ----
  __shared__ int hist[NBK_MAX];
  __shared__ int bbase[NBK_MAX];
  __shared__ int curloc[NBK_MAX];
  const int e0 = (blk - 56) * 8192;
  for (int i = tid; i < NBK; i += 1024) {
    hist[i] = 0;
    curloc[i] = 0;
  }
  __syncthreads();
  int bk[8];
  unsigned pk[8];
#pragma unroll
  for (int u = 0; u < 8; u++) {
    const int e = e0 + u * 1024 + tid;
    bk[u] = -1;
    pk[u] = 0;
    if (e < E) {
      const int d = dst[e];
      if ((unsigned)d < (unsigned)N) {
        int s = src[e];
        if ((unsigned)s >= (unsigned)N) s = 0;
        bk[u] = d >> 9;
        pk[u] = ((unsigned)s << 9) | (unsigned)(d & 511);
        atomicAdd(&hist[bk[u]], 1);
      }
    }
  }
  __syncthreads();
  // reserve one contiguous run per (block, bucket)
  for (int i = tid; i < NBK; i += 1024)
    if (hist[i]) bbase[i] = atomicAdd(&gcur[i], hist[i]);
  __syncthreads();
#pragma unroll
  for (int u = 0; u < 8; u++) {
    if (bk[u] >= 0) {
      const int gp = bbase[bk[u]] + atomicAdd(&curloc[bk[u]], 1);
      if (gp < CAP) ebuf[(size_t)bk[u] * CAP + gp] = pk[u];
    }
  }
}

// ==== K2: bucket-local {degree count + prefix + CSR scatter} (blocks
// 0..NBK-1) + encoder (blocks NBK..): hb = bf16(x @ W_enc + b_enc), h8 = fp8.
// Round-3 structure (measured 431 µs): LDS-staged double-buffered encoder.
__global__ __launch_bounds__(256) void scatter_enc_kernel(
    const unsigned* __restrict__ ebuf, const int* __restrict__ gcur,
    int* __restrict__ row_start, float* __restrict__ inv_deg,
    int* __restrict__ csr_src, const float* __restrict__ x,
    const unsigned short* __restrict__ wt, const float* __restrict__ b,
    unsigned short* __restrict__ hb, unsigned char* __restrict__ h8, int N,
    int NBK, int CAP) {
  __shared__ __align__(16) unsigned char smem[16384];
  if (blockIdx.x < (unsigned)NBK) {
    int* cur = (int*)smem;           // [512]
    int* rsl = (int*)(smem + 2048);  // [512]
    int* psc = (int*)(smem + 4096);  // [256]
    int* soffp = (int*)(smem + 5120);
    const int bkt = blockIdx.x;
    const int nodeBase = bkt << 9;
    const int tid = threadIdx.x;
    cur[tid] = 0;
    cur[tid + 256] = 0;
    __syncthreads();
    int cnt_b = gcur[bkt];
    if (cnt_b > CAP) cnt_b = CAP;
    const unsigned* eb = ebuf + (size_t)bkt * CAP;
    // pass 1: per-node degree via LDS atomics
    for (int i = tid; i < cnt_b; i += 256) atomicAdd(&cur[eb[i] & 511], 1);
    // bucket global offset = sum of preceding buckets' edge counts
    if (tid < 64) {
      int s = 0;
      for (int b2 = tid; b2 < bkt; b2 += 64) s += gcur[b2];
#pragma unroll
      for (int off = 32; off > 0; off >>= 1) s += __shfl_down(s, off, 64);
      if (tid == 0) *soffp = s;
    }
    __syncthreads();
    // local exclusive prefix over 512 degrees (pairwise + Hillis-Steele)
    const int d0 = cur[2 * tid];
    const int d1 = cur[2 * tid + 1];
    psc[tid] = d0 + d1;
    __syncthreads();
    for (int off = 1; off < 256; off <<= 1) {
      int t = (tid >= off) ? psc[tid - off] : 0;
      __syncthreads();
      psc[tid] += t;
      __syncthreads();
    }
    const int soff = *soffp;
    const int base0 = soff + psc[tid] - (d0 + d1);
    rsl[2 * tid] = base0;
    rsl[2 * tid + 1] = base0 + d0;
    const int g0 = nodeBase + 2 * tid;
    const int g1 = g0 + 1;
    if (g0 < N) {
      row_start[g0] = base0;
      inv_deg[g0] = d0 ? 1.0f / (float)d0 : 0.f;
    }
    if (g1 < N) {
      row_start[g1] = base0 + d0;
      inv_deg[g1] = d1 ? 1.0f / (float)d1 : 0.f;
    }
    if (bkt == NBK - 1 && tid == 255) row_start[N] = soff + psc[255];
    // reset cursors for pass 2
    cur[tid] = 0;
    cur[tid + 256] = 0;
    __syncthreads();
    // pass 2: rank-based scatter into the bucket's contiguous CSR window
    for (int i = tid; i < cnt_b; i += 256) {
      const unsigned p = eb[i];
      const int dl = p & 511;
      const int pos = rsl[dl] + atomicAdd(&cur[dl], 1);
      csr_src[pos] = (int)(p >> 9);
    }
    return;
  }
  // ---- encoder ----
  uint4(*sx)[256] = (uint4(*)[256])smem;
  uint4(*sw)[256] = (uint4(*)[256])(smem + 8192);
  const int t = threadIdx.x;
  const int lane = t & 63;
  const int wid = t >> 6;
  const int m15 = lane & 15;
  const int quad = lane >> 4;
  const int blockBase = (blockIdx.x - NBK) * 64;

  const int rs = t >> 2;
  const int qs = t & 3;
  const int us = rs * 4 + (qs ^ ((rs >> 1) & 3));
  const int gn = blockBase + rs;
  const bool valid = gn < N;
  const float* xp = x + (size_t)(valid ? gn : 0) * KIN + qs * 8;
  const unsigned short* wp = wt + (size_t)rs * KIN + qs * 8;

  const int arow = wid * 16 + m15;
  const int ua = arow * 4 + (quad ^ ((arow >> 1) & 3));
  int ub[4];
#pragma unroll
  for (int c4 = 0; c4 < 4; c4++) {
    const int col = c4 * 16 + m15;
    ub[c4] = col * 4 + (quad ^ ((col >> 1) & 3));
  }

  floatx4 acc[4];
#pragma unroll
  for (int c4 = 0; c4 < 4; c4++)
#pragma unroll
    for (int j = 0; j < 4; j++) acc[c4][j] = 0.f;

  float4 fx0, fx1;
  uint4 wv;
  if (valid) {
    fx0 = *(const float4*)(xp);
    fx1 = *(const float4*)(xp + 4);
  } else {
    fx0 = fx1 = make_float4(0.f, 0.f, 0.f, 0.f);
  }
  wv = *(const uint4*)(wp);

  for (int kc = 0; kc < 16; kc++) {
    const int curb = kc & 1;
    uint4 xu;
    xu.x = bf16pair(fx0.x, fx0.y);
    xu.y = bf16pair(fx0.z, fx0.w);
    xu.z = bf16pair(fx1.x, fx1.y);
    xu.w = bf16pair(fx1.z, fx1.w);
    sx[curb][us] = xu;
    sw[curb][us] = wv;
    __syncthreads();
    if (kc < 15) {
      const int ko = (kc + 1) * 32;
      if (valid) {
        fx0 = *(const float4*)(xp + ko);
        fx1 = *(const float4*)(xp + ko + 4);
      }
      wv = *(const uint4*)(wp + ko);
    }
    const short8 a = __builtin_bit_cast(short8, sx[curb][ua]);
#pragma unroll
    for (int c4 = 0; c4 < 4; c4++) {
      const short8 bf = __builtin_bit_cast(short8, sw[curb][ub[c4]]);
      acc[c4] =
          __builtin_amdgcn_mfma_f32_16x16x32_bf16(a, bf, acc[c4], 0, 0, 0);
    }
  }

#pragma unroll
  for (int c4 = 0; c4 < 4; c4++) {
    const float bias = b[c4 * 16 + m15];
#pragma unroll
    for (int r = 0; r < 4; r++) {
      const int row = blockBase + wid * 16 + quad * 4 + r;
      if (row < N) {
        const float v = acc[c4][r] + bias;
        hb[(size_t)row * HID + c4 * 16 + m15] = bf16one(v);
        h8[(size_t)row * HID + c4 * 16 + m15] = fp8q(v);
      }
    }
  }
}

// ===== fused layer: fp8 gather-mean -> [agg|h]@[Wl;Wr] MFMA -> residual/relu
//       -> bf16(+fp8) store (+ optional classifier on last layer) =====
// Round-2 structure (proven): Wl/Wr LDS-staged, 32 KB LDS total
__global__ __launch_bounds__(256) void layer_kernel(
    const unsigned short* __restrict__ hin,
    const unsigned char* __restrict__ h8in, unsigned short* __restrict__ hout,
    unsigned char* __restrict__ h8out, const int* __restrict__ row_start,
    const int* __restrict__ csr_src, const float* __restrict__ inv_deg,
    const unsigned short* __restrict__ Wlt,
    const unsigned short* __restrict__ Wrt, const float* __restrict__ bl,
    const float* __restrict__ Wc, const float* __restrict__ bc,
    float* __restrict__ out, int N) {
  __shared__ uint4 sAgg[512];  // 8 KB agg tile (bf16)
  __shared__ uint4 sH[512];    // 8 KB own h rows (bf16)
  __shared__ uint4 sWl[512];   // 8 KB Wl^T bf16
  __shared__ uint4 sWr[512];   // 8 KB Wr^T bf16
  const int tid = threadIdx.x;
  const int lane = tid & 63;
  const int wid = tid >> 6;
  const int m15 = lane & 15;
  const int quad = lane >> 4;
  const int blockBase = blockIdx.x * 64;

  // ---- stage own h rows + both weight mats ----
  {
    const int r = tid >> 2;
    const int gp = tid & 3;
    const int g0 = gp * 2, g1 = gp * 2 + 1;
    const int u0 = r * 8 + (g0 ^ (r & 7));
    const int u1 = r * 8 + (g1 ^ (r & 7));
    const int gn = blockBase + r;
    if (gn < N) {
      const uint4* hp = (const uint4*)(hin + (size_t)gn * HID);
      sH[u0] = hp[g0];
      sH[u1] = hp[g1];
    } else {
      const uint4 z = make_uint4(0, 0, 0, 0);
      sH[u0] = z;
      sH[u1] = z;
    }
    const uint4* wl = (const uint4*)(Wlt + (size_t)r * HID);
    const uint4* wr = (const uint4*)(Wrt + (size_t)r * HID);
    sWl[u0] = wl[g0];
    sWl[u1] = wl[g1];
    sWr[u0] = wr[g0];
    sWr[u1] = wr[g1];
  }

  // ---- mean-aggregate neighbors (fp8 rows) into sAgg ----
  {
    const int slot = lane >> 2;  // 0..15: node slot
    const int qc = lane & 3;     // 0..3: 16B group (16 fp8 cols)
    const int nl = wid * 16 + slot;
    const int gn = blockBase + nl;
    float a[16];
#pragma unroll
    for (int c = 0; c < 16; c++) a[c] = 0.f;
    float id = 0.f;
    if (gn < N) {
      id = inv_deg[gn];
      const int s = row_start[gn];
      const int e = row_start[gn + 1];
      for (int j = s; j < e; j += 8) {
        int n[8];
        bool ok[8];
#pragma unroll
        for (int u = 0; u < 8; u++) {
          const int jj = j + u;
          ok[u] = jj < e;
          n[u] = csr_src[ok[u] ? jj : j];
        }
        uint4 v[8];
#pragma unroll
        for (int u = 0; u < 8; u++) {
          v[u] = *(const uint4*)(h8in + (size_t)n[u] * HID + qc * 16);
        }
#pragma unroll
        for (int u = 0; u < 8; u++) {
          if (!ok[u]) v[u] = make_uint4(0, 0, 0, 0);
#if __has_builtin(__builtin_amdgcn_cvt_pk_f32_fp8)
          {
            floatx2 p;
            p = __builtin_amdgcn_cvt_pk_f32_fp8((int)v[u].x, false);
            a[0] += p[0]; a[1] += p[1];
            p = __builtin_amdgcn_cvt_pk_f32_fp8((int)v[u].x, true);
            a[2] += p[0]; a[3] += p[1];
            p = __builtin_amdgcn_cvt_pk_f32_fp8((int)v[u].y, false);
            a[4] += p[0]; a[5] += p[1];
            p = __builtin_amdgcn_cvt_pk_f32_fp8((int)v[u].y, true);
            a[6] += p[0]; a[7] += p[1];
            p = __builtin_amdgcn_cvt_pk_f32_fp8((int)v[u].z, false);
            a[8] += p[0]; a[9] += p[1];
            p = __builtin_amdgcn_cvt_pk_f32_fp8((int)v[u].z, true);
            a[10] += p[0]; a[11] += p[1];
            p = __builtin_amdgcn_cvt_pk_f32_fp8((int)v[u].w, false);
            a[12] += p[0]; a[13] += p[1];
            p = __builtin_amdgcn_cvt_pk_f32_fp8((int)v[u].w, true);
            a[14] += p[0]; a[15] += p[1];
          }
#else
          a[0] += __builtin_amdgcn_cvt_f32_fp8(v[u].x, 0);
          a[1] += __builtin_amdgcn_cvt_f32_fp8(v[u].x, 1);
          a[2] += __builtin_amdgcn_cvt_f32_fp8(v[u].x, 2);
          a[3] += __builtin_amdgcn_cvt_f32_fp8(v[u].x, 3);
          a[4] += __builtin_amdgcn_cvt_f32_fp8(v[u].y, 0);
          a[5] += __builtin_amdgcn_cvt_f32_fp8(v[u].y, 1);
          a[6] += __builtin_amdgcn_cvt_f32_fp8(v[u].y, 2);
          a[7] += __builtin_amdgcn_cvt_f32_fp8(v[u].y, 3);
          a[8] += __builtin_amdgcn_cvt_f32_fp8(v[u].z, 0);
          a[9] += __builtin_amdgcn_cvt_f32_fp8(v[u].z, 1);
          a[10] += __builtin_amdgcn_cvt_f32_fp8(v[u].z, 2);
          a[11] += __builtin_amdgcn_cvt_f32_fp8(v[u].z, 3);
          a[12] += __builtin_amdgcn_cvt_f32_fp8(v[u].w, 0);
          a[13] += __builtin_amdgcn_cvt_f32_fp8(v[u].w, 1);
          a[14] += __builtin_amdgcn_cvt_f32_fp8(v[u].w, 2);
          a[15] += __builtin_amdgcn_cvt_f32_fp8(v[u].w, 3);
#endif
        }
      }
    }
    uint4 p0, p1;
    p0.x = bf16pair(a[0] * id, a[1] * id);
    p0.y = bf16pair(a[2] * id, a[3] * id);
    p0.z = bf16pair(a[4] * id, a[5] * id);
    p0.w = bf16pair(a[6] * id, a[7] * id);
    p1.x = bf16pair(a[8] * id, a[9] * id);
    p1.y = bf16pair(a[10] * id, a[11] * id);
    p1.z = bf16pair(a[12] * id, a[13] * id);
    p1.w = bf16pair(a[14] * id, a[15] * id);
    sAgg[nl * 8 + ((qc * 2) ^ (nl & 7))] = p0;
    sAgg[nl * 8 + ((qc * 2 + 1) ^ (nl & 7))] = p1;
  }
  __syncthreads();

  // ---- MFMA: acc = agg@Wl + h@Wr ----
  floatx4 acc[4];
#pragma unroll
  for (int c4 = 0; c4 < 4; c4++)
#pragma unroll
    for (int j = 0; j < 4; j++) acc[c4][j] = 0.f;

  const int arow = wid * 16 + m15;
#pragma unroll
  for (int c = 0; c < 2; c++) {
    const int ua = arow * 8 + ((c * 4 + quad) ^ (arow & 7));
    const short8 aA = __builtin_bit_cast(short8, sAgg[ua]);
    const short8 aH = __builtin_bit_cast(short8, sH[ua]);
#pragma unroll
    for (int c4 = 0; c4 < 4; c4++) {
      const int col = c4 * 16 + m15;
      const int ub = col * 8 + ((c * 4 + quad) ^ (col & 7));
      acc[c4] = __builtin_amdgcn_mfma_f32_16x16x32_bf16(
          aA, __builtin_bit_cast(short8, sWl[ub]), acc[c4], 0, 0, 0);
      acc[c4] = __builtin_amdgcn_mfma_f32_16x16x32_bf16(
          aH, __builtin_bit_cast(short8, sWr[ub]), acc[c4], 0, 0, 0);
    }
  }

  // ---- epilogue: residual + bias + relu; bf16(+fp8) store; optional cls ----
  float vals[4][4];
#pragma unroll
  for (int c4 = 0; c4 < 4; c4++) {
    const float bias = bl[c4 * 16 + m15];
#pragma unroll
    for (int r = 0; r < 4; r++) {
      const int rowl = wid * 16 + quad * 4 + r;
      const unsigned short hv =
          ((const unsigned short*)
               sH)[(rowl * 8 + ((c4 * 2 + (m15 >> 3)) ^ (rowl & 7))) * 8 +
                   (m15 & 7)];
      const float v = __uint_as_float((unsigned)hv << 16) + acc[c4][r] + bias;
      vals[c4][r] = v > 0.f ? v : 0.f;
    }
  }
#pragma unroll
  for (int c4 = 0; c4 < 4; c4++) {
#pragma unroll
    for (int r = 0; r < 4; r++) {
      const int rowg = blockBase + wid * 16 + quad * 4 + r;
      if (rowg < N)
        hout[(size_t)rowg * HID + c4 * 16 + m15] = bf16one(vals[c4][r]);
    }
  }
  if (h8out != nullptr) {
#pragma unroll
    for (int c4 = 0; c4 < 4; c4++) {
#pragma unroll
      for (int r = 0; r < 4; r++) {
        const int rowg = blockBase + wid * 16 + quad * 4 + r;
        if (rowg < N)
          h8out[(size_t)rowg * HID + c4 * 16 + m15] = fp8q(vals[c4][r]);
      }
    }
  }
  if (Wc != nullptr) {
    float p[4] = {0.f, 0.f, 0.f, 0.f};
#pragma unroll
    for (int c4 = 0; c4 < 4; c4++) {
      const float wc = Wc[c4 * 16 + m15];
#pragma unroll
      for (int r = 0; r < 4; r++) p[r] += vals[c4][r] * wc;
    }
#pragma unroll
    for (int off = 1; off < 16; off <<= 1) {
#pragma unroll
      for (int r = 0; r < 4; r++) p[r] += __shfl_xor(p[r], off, 16);
    }
    if (m15 == 0) {
      const float bb = bc[0];
#pragma unroll
      for (int r = 0; r < 4; r++) {
        const int rowg = blockBase + wid * 16 + quad * 4 + r;
        if (rowg < N) out[rowg] = 1.0f / (1.0f + expf(-(p[r] + bb)));
      }
    }
  }
}

extern "C" void kernel_launch(void* const* d_in, const int* in_sizes, int n_in,
                              void* d_out, int out_size, void* d_ws,
                              size_t ws_size, hipStream_t stream) {
  const float* x = (const float*)d_in[0];
  const int* ei = (const int*)d_in[1];
  const float* W_enc = (const float*)d_in[2];
  const float* b_enc = (const float*)d_in[3];
  const float* Wl = (const float*)d_in[4];
  const float* bl = (const float*)d_in[5];
  const float* Wr = (const float*)d_in[6];
  const float* Wc = (const float*)d_in[7];
  const float* bc = (const float*)d_in[8];
  float* out = (float*)d_out;

  const int N = in_sizes[0] / KIN;
  const int E = in_sizes[1] / 2;
  const int* src = ei;
  const int* dst = ei + E;

  const int NBK = (N + 511) >> 9;  // 512-node buckets
  int CAP = E / (NBK > 0 ? NBK : 1);
  CAP = CAP + (CAP >> 1) + 1024;  // 1.5x mean + slack (>>20 sigma headroom)
  CAP = (CAP + 255) & ~255;

  char* ws = (char*)d_ws;
  size_t off = 0;
  auto alloc = [&](size_t bytes) -> void* {
    void* p = ws + off;
    off += (bytes + 255) & ~(size_t)255;
    return p;
  };
  unsigned short* hb0 =
      (unsigned short*)alloc((size_t)N * HID * sizeof(unsigned short));
  unsigned short* hb1 =
      (unsigned short*)alloc((size_t)N * HID * sizeof(unsigned short));
  unsigned char* h8a = (unsigned char*)alloc((size_t)N * HID);
  unsigned char* h8b = (unsigned char*)alloc((size_t)N * HID);
  int* gcur = (int*)alloc((size_t)NBK * sizeof(int));  // zeroed below
  int* row_start = (int*)alloc((size_t)(N + 1) * sizeof(int));
  float* inv_deg = (float*)alloc((size_t)N * sizeof(float));
  int* csr_src = (int*)alloc((size_t)E * sizeof(int));
  unsigned* ebuf = (unsigned*)alloc((size_t)NBK * CAP * sizeof(unsigned));
  unsigned short* wte =
      (unsigned short*)alloc((size_t)HID * KIN * sizeof(unsigned short));
  unsigned short* wlrt =
      (unsigned short*)alloc((size_t)6 * HID * HID * sizeof(unsigned short));

  hipMemsetAsync(gcur, 0, (size_t)NBK * sizeof(int), stream);

  const int nbktA = (E + 8191) / 8192;
  prep_bucket_kernel<<<56 + nbktA, 1024, 0, stream>>>(
      W_enc, Wl, Wr, wte, wlrt, src, dst, gcur, ebuf, E, N, NBK, CAP);
  const int nb64 = (N + 63) / 64;
  scatter_enc_kernel<<<NBK + nb64, 256, 0, stream>>>(
      ebuf, gcur, row_start, inv_deg, csr_src, x, wte, b_enc, hb0, h8a, N, NBK,
      CAP);

  // layer 0: hb0/h8a -> hb1/h8b
  layer_kernel<<<nb64, 256, 0, stream>>>(hb0, h8a, hb1, h8b, row_start, csr_src,
                                         inv_deg, wlrt, wlrt + 3 * 4096, bl,
                                         nullptr, nullptr, nullptr, N);
  // layer 1: hb1/h8b -> hb0/h8a
  layer_kernel<<<nb64, 256, 0, stream>>>(hb1, h8b, hb0, h8a, row_start, csr_src,
                                         inv_deg, wlrt + 4096, wlrt + 4 * 4096,
                                         bl + 64, nullptr, nullptr, nullptr, N);
  // layer 2: hb0/h8a -> hb1 (no fp8 out), fused classifier
  layer_kernel<<<nb64, 256, 0, stream>>>(hb0, h8a, hb1, nullptr, row_start,
                                         csr_src, inv_deg, wlrt + 2 * 4096,
                                         wlrt + 5 * 4096, bl + 128, Wc, bc, out,
                                         N);
}